// Round 25
// baseline (79.217 us; speedup 1.0000x reference)
//
#include <hip/hip_runtime.h>
#include <stdint.h>

typedef __attribute__((ext_vector_type(8))) short short8;
typedef __attribute__((ext_vector_type(4))) float f32x4;

#define SEQ 256
#define NH 8

__device__ __forceinline__ uint32_t cvt_pk_bf16(float lo, float hi) {
  uint32_t r;
  asm("v_cvt_pk_bf16_f32 %0, %1, %2" : "=v"(r) : "v"(lo), "v"(hi));
  return r;
}

__device__ __forceinline__ short8 pack8(f32x4 a, f32x4 b) {
  union { uint32_t u[4]; short8 v; } t;
  t.u[0] = cvt_pk_bf16(a[0], a[1]);
  t.u[1] = cvt_pk_bf16(a[2], a[3]);
  t.u[2] = cvt_pk_bf16(b[0], b[1]);
  t.u[3] = cvt_pk_bf16(b[2], b[3]);
  return t.v;
}

// ---------------------------------------------------------------------------
// K1 (r3/r22-proven): w1t[h][k][p] = w1[p][k][h]. Coalesced one-time 96 KB.
// ---------------------------------------------------------------------------
__global__ __launch_bounds__(256) void transpose_w1(
    const float* __restrict__ w1, float* __restrict__ w1t) {
  int t = blockIdx.x * 256 + threadIdx.x;  // 24576
  int p = t % 96;
  int k = (t / 96) & 31;
  int h = t / 3072;
  w1t[t] = w1[p * 256 + k * 8 + h];
}

// ---------------------------------------------------------------------------
// K2: r18 fused body MINUS sW1. B-fragments read CONTIGUOUS (32B/lane) from
// w1t in global (L2-hot, r22-K2-proven pattern). LDS 36.9 KB + VGPR<=64
// (launch_bounds(512,8)) -> 4 blocks/CU co-resident (r18: 2). Same tile size
// => aggregate staging unchanged (the r23 trap avoided).
// Block = (b, h, 64m x 64n), 512 thr (8 waves), 512 blocks.
// ---------------------------------------------------------------------------
__global__ __launch_bounds__(512, 8) void dis_att_fused(
    const float* __restrict__ attn, const int* __restrict__ bseq,
    const int* __restrict__ cseq, const float* __restrict__ epos,
    const float* __restrict__ ebi, const float* __restrict__ ebj,
    const float* __restrict__ eci, const float* __restrict__ ecj,
    const float* __restrict__ w1t, const float* __restrict__ w2,
    const float* __restrict__ w3, float* __restrict__ out) {
  __shared__ float sAp[128][36];
  __shared__ float sAi[64][36];
  __shared__ float sAj[64][36];
  int tid = threadIdx.x;
  int wg = blockIdx.x;                     // 512 = b(4) h(8) mt(4) nt(4)
  int nt = wg & 3, mt = (wg >> 2) & 3, h = (wg >> 4) & 7, b = wg >> 7;
  int m0 = mt * 64, n0 = nt * 64;
  int f0 = m0 - n0 + 193;                  // global f of sAp row 0
  int lane = tid & 63, w = tid >> 6;
  int lcol = lane & 15, kb = lane >> 4, k8 = kb * 8;
  f32x4 zero = {0.f, 0.f, 0.f, 0.f};

  // ---------------- phase 0: coalesced staging (no sW1) ----------------
  {
    int r = tid >> 3, q = tid & 7;
#pragma unroll
    for (int p = 0; p < 2; ++p) {
      int row = r + 64 * p;
      int f = f0 + row; if (f > 511) f = 511;
      *(f32x4*)&sAp[row][q * 4] = *(const f32x4*)(epos + (f * NH + h) * 32 + q * 4);
    }
    int gmi = b * SEQ + m0 + r, gmj = b * SEQ + n0 + r;
    if (q < 4) {
      int bi = bseq[gmi], bj = bseq[gmj];
      *(f32x4*)&sAi[r][q * 4] = *(const f32x4*)(ebi + (bi * NH + h) * 16 + q * 4);
      *(f32x4*)&sAj[r][q * 4] = *(const f32x4*)(ebj + (bj * NH + h) * 16 + q * 4);
    } else {
      int ci = cseq[gmi], cj = cseq[gmj];
      *(f32x4*)&sAi[r][q * 4] = *(const f32x4*)(eci + (ci * NH + h) * 16 + (q - 4) * 4);
      *(f32x4*)&sAj[r][q * 4] = *(const f32x4*)(ecj + (cj * NH + h) * 16 + (q - 4) * 4);
    }
  }

  // B-fragments from w1t (global, contiguous 32B per lane; r22-K2-proven)
  short8 bf[2];
  {
    int p0 = (w < 4) ? k8
           : ((w < 6) ? ((kb < 2 ? 32 : 48) + k8)
                      : ((kb < 2 ? 48 : 64) + k8));
#pragma unroll
    for (int kt = 0; kt < 2; ++kt) {
      const float* wrow = w1t + h * 3072 + (kt * 16 + lcol) * 96 + p0;
      bf[kt] = pack8(*(const f32x4*)wrow, *(const f32x4*)(wrow + 4));
    }
  }
  __syncthreads();

  // ---------------- phase 1a: A-fragment reads (LDS -> regs) ----------------
  short8 af[2];
  int isI = w < 6;
  int w2_ = isI ? (w - 4) : (w - 6);
#pragma unroll
  for (int t = 0; t < 2; ++t) {
    int row = ((w < 4) ? (w + t * 4) : (w2_ * 2 + t)) * 16 + lcol;
    const float* base = (w < 4) ? &sAp[row][0]
                                : (isI ? &sAi[row][0] : &sAj[row][0]);
    af[t] = pack8(*(const f32x4*)(base + k8), *(const f32x4*)(base + k8 + 4));
  }
  __syncthreads();                         // all raw reads done

  // ---------------- phase 1b: MFMA + in-place writes ----------------
#pragma unroll
  for (int t = 0; t < 2; ++t) {
#pragma unroll
    for (int kt = 0; kt < 2; ++kt) {
      f32x4 d = __builtin_amdgcn_mfma_f32_16x16x32_bf16(af[t], bf[kt], zero, 0, 0, 0);
      if (w < 4) {
        int mt_ = w + t * 4;
#pragma unroll
        for (int r = 0; r < 4; ++r)
          sAp[mt_ * 16 + kb * 4 + r][kt * 16 + lcol] = d[r];
      } else {
        int mt_ = w2_ * 2 + t;
#pragma unroll
        for (int r = 0; r < 4; ++r) {
          float* T = isI ? &sAi[mt_ * 16 + kb * 4 + r][kt * 16 + lcol]
                         : &sAj[mt_ * 16 + kb * 4 + r][kt * 16 + lcol];
          *T = d[r];
        }
      }
    }
  }
  __syncthreads();

  // ---------------- phase 2: main compute (r18 verbatim) ----------------
  union { uint32_t u[4]; short8 v; } w2f;  // A = w2^T: row=lcol, k=k8..k8+7
#pragma unroll
  for (int r = 0; r < 4; ++r) {
    float lo = w2[(k8 + 2 * r) * 128 + lcol * 8 + h];
    float hi = w2[(k8 + 2 * r + 1) * 128 + lcol * 8 + h];
    w2f.u[r] = cvt_pk_bf16(lo, hi);
  }
  float w3v[4];
#pragma unroll
  for (int r = 0; r < 4; ++r) w3v[r] = w3[(kb * 4 + r) * 8 + h];

  f32x4 ajA[4], ajB[4];
#pragma unroll
  for (int ng = 0; ng < 4; ++ng) {
    int nl = ng * 16 + lcol;
    ajA[ng] = *(const f32x4*)&sAj[nl][k8];
    ajB[ng] = *(const f32x4*)&sAj[nl][k8 + 4];
  }

  const float* attn_b = attn + (b * NH + h) * SEQ * SEQ;
  float* out_b = out + (b * NH + h) * SEQ * SEQ;
  int bit4 = kb & 1, bit5 = kb & 2;

#pragma unroll
  for (int s = 0; s < 2; ++s) {
    int mb = w * 8 + s * 4;
    float av[4];
    int idxs[4];
#pragma unroll
    for (int ng = 0; ng < 4; ++ng) {
      idxs[ng] = (m0 + mb + kb) * SEQ + n0 + ng * 16 + lcol;
      av[ng] = attn_b[idxs[ng]];
    }
    f32x4 aiA[4], aiB[4];
#pragma unroll
    for (int mi = 0; mi < 4; ++mi) {
      aiA[mi] = *(const f32x4*)&sAi[mb + mi][k8];
      aiB[mi] = *(const f32x4*)&sAi[mb + mi][k8 + 4];
    }
#pragma unroll
    for (int ng = 0; ng < 4; ++ng) {
      int nl = ng * 16 + lcol;
      f32x4 pA[4], pB[4];
#pragma unroll
      for (int mi = 0; mi < 4; ++mi) {
        int rl = mb + mi - nl + 63;
        pA[mi] = *(const f32x4*)&sAp[rl][k8];
        pB[mi] = *(const f32x4*)&sAp[rl][k8 + 4];
      }
      __builtin_amdgcn_sched_barrier(0);
      float part[4];
#pragma unroll
      for (int mi = 0; mi < 4; ++mi) {
        f32x4 s0 = pA[mi] + aiA[mi] + ajA[ng];
        f32x4 s1 = pB[mi] + aiB[mi] + ajB[ng];
        union { uint32_t u[4]; short8 v; } ef;
        ef.u[0] = cvt_pk_bf16(fmaxf(s0[0], 0.f), fmaxf(s0[1], 0.f));
        ef.u[1] = cvt_pk_bf16(fmaxf(s0[2], 0.f), fmaxf(s0[3], 0.f));
        ef.u[2] = cvt_pk_bf16(fmaxf(s1[0], 0.f), fmaxf(s1[1], 0.f));
        ef.u[3] = cvt_pk_bf16(fmaxf(s1[2], 0.f), fmaxf(s1[3], 0.f));
        f32x4 d = __builtin_amdgcn_mfma_f32_16x16x32_bf16(w2f.v, ef.v, zero, 0, 0, 0);
        part[mi] = fmaxf(d[0], 0.f) * w3v[0] + fmaxf(d[1], 0.f) * w3v[1] +
                   fmaxf(d[2], 0.f) * w3v[2] + fmaxf(d[3], 0.f) * w3v[3];
      }
      float mineA = bit4 ? part[1] : part[0];
      float sendA = bit4 ? part[0] : part[1];
      float mineB = bit4 ? part[3] : part[2];
      float sendB = bit4 ? part[2] : part[3];
      mineA += __shfl_xor(sendA, 16, 64);
      mineB += __shfl_xor(sendB, 16, 64);
      float keep = bit5 ? mineB : mineA;
      float send = bit5 ? mineA : mineB;
      float res = keep + __shfl_xor(send, 32, 64);
      out_b[idxs[ng]] = av[ng] + res;
    }
  }
}

extern "C" void kernel_launch(void* const* d_in, const int* in_sizes, int n_in,
                              void* d_out, int out_size, void* d_ws, size_t ws_size,
                              hipStream_t stream) {
  const float* attn = (const float*)d_in[0];
  const int* bseq   = (const int*)d_in[1];
  const int* cseq   = (const int*)d_in[2];
  const float* epos = (const float*)d_in[3];
  const float* ebi  = (const float*)d_in[4];
  const float* ebj  = (const float*)d_in[5];
  const float* eci  = (const float*)d_in[6];
  const float* ecj  = (const float*)d_in[7];
  const float* w1   = (const float*)d_in[8];
  const float* w2   = (const float*)d_in[9];
  const float* w3   = (const float*)d_in[10];
  float* out = (float*)d_out;

  float* w1t = (float*)d_ws;               // 8*32*96 = 24576 f32 (96 KB)

  hipLaunchKernelGGL(transpose_w1, dim3(96), dim3(256), 0, stream, w1, w1t);
  hipLaunchKernelGGL(dis_att_fused, dim3(512), dim3(512), 0, stream,
                     attn, bseq, cseq, epos, ebi, ebj, eci, ecj, w1t, w2, w3, out);
}

// Round 26
// 25.329 us; speedup vs baseline: 3.1275x; 3.1275x over previous
//
#include <hip/hip_runtime.h>
#include <stdint.h>

typedef __attribute__((ext_vector_type(8))) short short8;
typedef __attribute__((ext_vector_type(4))) float f32x4;

#define SEQ 256
#define NH 8

__device__ __forceinline__ uint32_t cvt_pk_bf16(float lo, float hi) {
  uint32_t r;
  asm("v_cvt_pk_bf16_f32 %0, %1, %2" : "=v"(r) : "v"(lo), "v"(hi));
  return r;
}

__device__ __forceinline__ short8 pack8(f32x4 a, f32x4 b) {
  union { uint32_t u[4]; short8 v; } t;
  t.u[0] = cvt_pk_bf16(a[0], a[1]);
  t.u[1] = cvt_pk_bf16(a[2], a[3]);
  t.u[2] = cvt_pk_bf16(b[0], b[1]);
  t.u[3] = cvt_pk_bf16(b[2], b[3]);
  return t.v;
}

// ---------------------------------------------------------------------------
// K1 (r3/r22-proven): w1t[h][k][p] = w1[p][k][h]. Coalesced one-time 96 KB.
// ---------------------------------------------------------------------------
__global__ __launch_bounds__(256) void transpose_w1(
    const float* __restrict__ w1, float* __restrict__ w1t) {
  int t = blockIdx.x * 256 + threadIdx.x;  // 24576
  int p = t % 96;
  int k = (t / 96) & 31;
  int h = t / 3072;
  w1t[t] = w1[p * 256 + k * 8 + h];
}

// ---------------------------------------------------------------------------
// K2: r18 fused body MINUS sW1; B-fragments contiguous from w1t (L2-hot).
// launch_bounds(512,4): VGPR cap 128 (natural ~64, NO spill -- r25's (512,8)
// forced VGPR=32 and spilled 137MB/dispatch). LDS 36.9 KB -> 4 blocks/CU
// co-resident (32 waves/CU, 2x r18) at unchanged tile size.
// Block = (b, h, 64m x 64n), 512 thr (8 waves), 512 blocks.
// ---------------------------------------------------------------------------
__global__ __launch_bounds__(512, 4) void dis_att_fused(
    const float* __restrict__ attn, const int* __restrict__ bseq,
    const int* __restrict__ cseq, const float* __restrict__ epos,
    const float* __restrict__ ebi, const float* __restrict__ ebj,
    const float* __restrict__ eci, const float* __restrict__ ecj,
    const float* __restrict__ w1t, const float* __restrict__ w2,
    const float* __restrict__ w3, float* __restrict__ out) {
  __shared__ float sAp[128][36];
  __shared__ float sAi[64][36];
  __shared__ float sAj[64][36];
  int tid = threadIdx.x;
  int wg = blockIdx.x;                     // 512 = b(4) h(8) mt(4) nt(4)
  int nt = wg & 3, mt = (wg >> 2) & 3, h = (wg >> 4) & 7, b = wg >> 7;
  int m0 = mt * 64, n0 = nt * 64;
  int f0 = m0 - n0 + 193;                  // global f of sAp row 0
  int lane = tid & 63, w = tid >> 6;
  int lcol = lane & 15, kb = lane >> 4, k8 = kb * 8;
  f32x4 zero = {0.f, 0.f, 0.f, 0.f};

  // ---------------- phase 0: coalesced staging (no sW1) ----------------
  {
    int r = tid >> 3, q = tid & 7;
#pragma unroll
    for (int p = 0; p < 2; ++p) {
      int row = r + 64 * p;
      int f = f0 + row; if (f > 511) f = 511;
      *(f32x4*)&sAp[row][q * 4] = *(const f32x4*)(epos + (f * NH + h) * 32 + q * 4);
    }
    int gmi = b * SEQ + m0 + r, gmj = b * SEQ + n0 + r;
    if (q < 4) {
      int bi = bseq[gmi], bj = bseq[gmj];
      *(f32x4*)&sAi[r][q * 4] = *(const f32x4*)(ebi + (bi * NH + h) * 16 + q * 4);
      *(f32x4*)&sAj[r][q * 4] = *(const f32x4*)(ebj + (bj * NH + h) * 16 + q * 4);
    } else {
      int ci = cseq[gmi], cj = cseq[gmj];
      *(f32x4*)&sAi[r][q * 4] = *(const f32x4*)(eci + (ci * NH + h) * 16 + (q - 4) * 4);
      *(f32x4*)&sAj[r][q * 4] = *(const f32x4*)(ecj + (cj * NH + h) * 16 + (q - 4) * 4);
    }
  }

  // B-fragments from w1t (global, contiguous 32B per lane; r22-K2-proven)
  short8 bf[2];
  {
    int p0 = (w < 4) ? k8
           : ((w < 6) ? ((kb < 2 ? 32 : 48) + k8)
                      : ((kb < 2 ? 48 : 64) + k8));
#pragma unroll
    for (int kt = 0; kt < 2; ++kt) {
      const float* wrow = w1t + h * 3072 + (kt * 16 + lcol) * 96 + p0;
      bf[kt] = pack8(*(const f32x4*)wrow, *(const f32x4*)(wrow + 4));
    }
  }
  __syncthreads();

  // ---------------- phase 1a: A-fragment reads (LDS -> regs) ----------------
  short8 af[2];
  int isI = w < 6;
  int w2_ = isI ? (w - 4) : (w - 6);
#pragma unroll
  for (int t = 0; t < 2; ++t) {
    int row = ((w < 4) ? (w + t * 4) : (w2_ * 2 + t)) * 16 + lcol;
    const float* base = (w < 4) ? &sAp[row][0]
                                : (isI ? &sAi[row][0] : &sAj[row][0]);
    af[t] = pack8(*(const f32x4*)(base + k8), *(const f32x4*)(base + k8 + 4));
  }
  __syncthreads();                         // all raw reads done

  // ---------------- phase 1b: MFMA + in-place writes ----------------
#pragma unroll
  for (int t = 0; t < 2; ++t) {
#pragma unroll
    for (int kt = 0; kt < 2; ++kt) {
      f32x4 d = __builtin_amdgcn_mfma_f32_16x16x32_bf16(af[t], bf[kt], zero, 0, 0, 0);
      if (w < 4) {
        int mt_ = w + t * 4;
#pragma unroll
        for (int r = 0; r < 4; ++r)
          sAp[mt_ * 16 + kb * 4 + r][kt * 16 + lcol] = d[r];
      } else {
        int mt_ = w2_ * 2 + t;
#pragma unroll
        for (int r = 0; r < 4; ++r) {
          float* T = isI ? &sAi[mt_ * 16 + kb * 4 + r][kt * 16 + lcol]
                         : &sAj[mt_ * 16 + kb * 4 + r][kt * 16 + lcol];
          *T = d[r];
        }
      }
    }
  }
  __syncthreads();

  // ---------------- phase 2: main compute (r18 verbatim) ----------------
  union { uint32_t u[4]; short8 v; } w2f;  // A = w2^T: row=lcol, k=k8..k8+7
#pragma unroll
  for (int r = 0; r < 4; ++r) {
    float lo = w2[(k8 + 2 * r) * 128 + lcol * 8 + h];
    float hi = w2[(k8 + 2 * r + 1) * 128 + lcol * 8 + h];
    w2f.u[r] = cvt_pk_bf16(lo, hi);
  }
  float w3v[4];
#pragma unroll
  for (int r = 0; r < 4; ++r) w3v[r] = w3[(kb * 4 + r) * 8 + h];

  f32x4 ajA[4], ajB[4];
#pragma unroll
  for (int ng = 0; ng < 4; ++ng) {
    int nl = ng * 16 + lcol;
    ajA[ng] = *(const f32x4*)&sAj[nl][k8];
    ajB[ng] = *(const f32x4*)&sAj[nl][k8 + 4];
  }

  const float* attn_b = attn + (b * NH + h) * SEQ * SEQ;
  float* out_b = out + (b * NH + h) * SEQ * SEQ;
  int bit4 = kb & 1, bit5 = kb & 2;

#pragma unroll
  for (int s = 0; s < 2; ++s) {
    int mb = w * 8 + s * 4;
    float av[4];
    int idxs[4];
#pragma unroll
    for (int ng = 0; ng < 4; ++ng) {
      idxs[ng] = (m0 + mb + kb) * SEQ + n0 + ng * 16 + lcol;
      av[ng] = attn_b[idxs[ng]];
    }
    f32x4 aiA[4], aiB[4];
#pragma unroll
    for (int mi = 0; mi < 4; ++mi) {
      aiA[mi] = *(const f32x4*)&sAi[mb + mi][k8];
      aiB[mi] = *(const f32x4*)&sAi[mb + mi][k8 + 4];
    }
#pragma unroll
    for (int ng = 0; ng < 4; ++ng) {
      int nl = ng * 16 + lcol;
      f32x4 pA[4], pB[4];
#pragma unroll
      for (int mi = 0; mi < 4; ++mi) {
        int rl = mb + mi - nl + 63;
        pA[mi] = *(const f32x4*)&sAp[rl][k8];
        pB[mi] = *(const f32x4*)&sAp[rl][k8 + 4];
      }
      __builtin_amdgcn_sched_barrier(0);
      float part[4];
#pragma unroll
      for (int mi = 0; mi < 4; ++mi) {
        f32x4 s0 = pA[mi] + aiA[mi] + ajA[ng];
        f32x4 s1 = pB[mi] + aiB[mi] + ajB[ng];
        union { uint32_t u[4]; short8 v; } ef;
        ef.u[0] = cvt_pk_bf16(fmaxf(s0[0], 0.f), fmaxf(s0[1], 0.f));
        ef.u[1] = cvt_pk_bf16(fmaxf(s0[2], 0.f), fmaxf(s0[3], 0.f));
        ef.u[2] = cvt_pk_bf16(fmaxf(s1[0], 0.f), fmaxf(s1[1], 0.f));
        ef.u[3] = cvt_pk_bf16(fmaxf(s1[2], 0.f), fmaxf(s1[3], 0.f));
        f32x4 d = __builtin_amdgcn_mfma_f32_16x16x32_bf16(w2f.v, ef.v, zero, 0, 0, 0);
        part[mi] = fmaxf(d[0], 0.f) * w3v[0] + fmaxf(d[1], 0.f) * w3v[1] +
                   fmaxf(d[2], 0.f) * w3v[2] + fmaxf(d[3], 0.f) * w3v[3];
      }
      float mineA = bit4 ? part[1] : part[0];
      float sendA = bit4 ? part[0] : part[1];
      float mineB = bit4 ? part[3] : part[2];
      float sendB = bit4 ? part[2] : part[3];
      mineA += __shfl_xor(sendA, 16, 64);
      mineB += __shfl_xor(sendB, 16, 64);
      float keep = bit5 ? mineB : mineA;
      float send = bit5 ? mineA : mineB;
      float res = keep + __shfl_xor(send, 32, 64);
      out_b[idxs[ng]] = av[ng] + res;
    }
  }
}

extern "C" void kernel_launch(void* const* d_in, const int* in_sizes, int n_in,
                              void* d_out, int out_size, void* d_ws, size_t ws_size,
                              hipStream_t stream) {
  const float* attn = (const float*)d_in[0];
  const int* bseq   = (const int*)d_in[1];
  const int* cseq   = (const int*)d_in[2];
  const float* epos = (const float*)d_in[3];
  const float* ebi  = (const float*)d_in[4];
  const float* ebj  = (const float*)d_in[5];
  const float* eci  = (const float*)d_in[6];
  const float* ecj  = (const float*)d_in[7];
  const float* w1   = (const float*)d_in[8];
  const float* w2   = (const float*)d_in[9];
  const float* w3   = (const float*)d_in[10];
  float* out = (float*)d_out;

  float* w1t = (float*)d_ws;               // 8*32*96 = 24576 f32 (96 KB)

  hipLaunchKernelGGL(transpose_w1, dim3(96), dim3(256), 0, stream, w1, w1t);
  hipLaunchKernelGGL(dis_att_fused, dim3(512), dim3(512), 0, stream,
                     attn, bseq, cseq, epos, ebi, ebj, eci, ecj, w1t, w2, w3, out);
}

// Round 27
// 22.104 us; speedup vs baseline: 3.5839x; 1.1459x over previous
//
#include <hip/hip_runtime.h>
#include <stdint.h>

typedef __attribute__((ext_vector_type(8))) short short8;
typedef __attribute__((ext_vector_type(4))) float f32x4;

#define SEQ 256
#define NH 8

__device__ __forceinline__ uint32_t cvt_pk_bf16(float lo, float hi) {
  uint32_t r;
  asm("v_cvt_pk_bf16_f32 %0, %1, %2" : "=v"(r) : "v"(lo), "v"(hi));
  return r;
}

__device__ __forceinline__ short8 pack8(f32x4 a, f32x4 b) {
  union { uint32_t u[4]; short8 v; } t;
  t.u[0] = cvt_pk_bf16(a[0], a[1]);
  t.u[1] = cvt_pk_bf16(a[2], a[3]);
  t.u[2] = cvt_pk_bf16(b[0], b[1]);
  t.u[3] = cvt_pk_bf16(b[2], b[3]);
  return t.v;
}

// ---------------------------------------------------------------------------
// ONE fused kernel (r18 = session best, 22.05-22.25us across runs).
// Block = (b,h,64m x 64n), 512 thr (8 waves), 512 blocks.
// Phase 0: coalesced staging: sW1 <- w1[:,:,h] (12.7 KB); sAp <- raw epos
//   band (128 rows x 32, f32x4 8 thr/row); sAi/sAj <- raw emb rows
//   ([ebi|eci] / [ebj|ecj], one 64B row-half per 4 threads).
// Phase 1: A-fragments via ds_read from raw LDS; B-fragments from sW1;
//   MFMA into regs (r5-validated conventions); barrier; write D IN-PLACE.
// Phase 2: batched pA/pB chains, e1=relu(Ap+Ai+Aj)->bf16, mfma(A=w2^T),
//   relu-dot w3, 3-shuffle butterfly reduce, coalesced attn-add store.
// ---------------------------------------------------------------------------
__global__ __launch_bounds__(512, 4) void dis_att_fused(
    const float* __restrict__ attn, const int* __restrict__ bseq,
    const int* __restrict__ cseq, const float* __restrict__ epos,
    const float* __restrict__ ebi, const float* __restrict__ ebj,
    const float* __restrict__ eci, const float* __restrict__ ecj,
    const float* __restrict__ w1, const float* __restrict__ w2,
    const float* __restrict__ w3, float* __restrict__ out) {
  __shared__ float sW1[96][33];
  __shared__ float sAp[128][36];
  __shared__ float sAi[64][36];
  __shared__ float sAj[64][36];
  int tid = threadIdx.x;
  int wg = blockIdx.x;                     // 512 = b(4) h(8) mt(4) nt(4)
  int nt = wg & 3, mt = (wg >> 2) & 3, h = (wg >> 4) & 7, b = wg >> 7;
  int m0 = mt * 64, n0 = nt * 64;
  int f0 = m0 - n0 + 193;                  // global f of sAp row 0
  int lane = tid & 63, w = tid >> 6;
  int lcol = lane & 15, kb = lane >> 4, k8 = kb * 8;
  f32x4 zero = {0.f, 0.f, 0.f, 0.f};

  // ---------------- phase 0: coalesced staging ----------------
#pragma unroll
  for (int i = 0; i < 6; ++i) {
    int idx = tid + 512 * i;               // p*32 + k, 3072 total
    sW1[idx >> 5][idx & 31] = w1[(idx >> 5) * 256 + (idx & 31) * 8 + h];
  }
  {
    int r = tid >> 3, q = tid & 7;
#pragma unroll
    for (int p = 0; p < 2; ++p) {
      int row = r + 64 * p;
      int f = f0 + row; if (f > 511) f = 511;
      *(f32x4*)&sAp[row][q * 4] = *(const f32x4*)(epos + (f * NH + h) * 32 + q * 4);
    }
    int gmi = b * SEQ + m0 + r, gmj = b * SEQ + n0 + r;
    if (q < 4) {
      int bi = bseq[gmi], bj = bseq[gmj];
      *(f32x4*)&sAi[r][q * 4] = *(const f32x4*)(ebi + (bi * NH + h) * 16 + q * 4);
      *(f32x4*)&sAj[r][q * 4] = *(const f32x4*)(ebj + (bj * NH + h) * 16 + q * 4);
    } else {
      int ci = cseq[gmi], cj = cseq[gmj];
      *(f32x4*)&sAi[r][q * 4] = *(const f32x4*)(eci + (ci * NH + h) * 16 + (q - 4) * 4);
      *(f32x4*)&sAj[r][q * 4] = *(const f32x4*)(ecj + (cj * NH + h) * 16 + (q - 4) * 4);
    }
  }
  __syncthreads();

  // ---------------- phase 1a: fragment reads (LDS -> regs) ----------------
  short8 af[2], bf[2];
  if (w < 4) {                             // Apos: tiles {w, w+4}
#pragma unroll
    for (int kt = 0; kt < 2; ++kt) {
      union { uint32_t u[4]; short8 v; } t;
#pragma unroll
      for (int r = 0; r < 4; ++r)
        t.u[r] = cvt_pk_bf16(sW1[k8 + 2 * r][kt * 16 + lcol],
                             sW1[k8 + 2 * r + 1][kt * 16 + lcol]);
      bf[kt] = t.v;
    }
#pragma unroll
    for (int t = 0; t < 2; ++t) {
      int row = (w + t * 4) * 16 + lcol;
      af[t] = pack8(*(const f32x4*)&sAp[row][k8],
                    *(const f32x4*)&sAp[row][k8 + 4]);
    }
  } else {                                 // Ai (waves 4,5) / Aj (waves 6,7)
    int isI = w < 6;
    int p0 = isI ? ((kb < 2 ? 32 : 48) + k8)
                 : ((kb < 2 ? 48 : 64) + k8);
#pragma unroll
    for (int kt = 0; kt < 2; ++kt) {
      union { uint32_t u[4]; short8 v; } t;
#pragma unroll
      for (int r = 0; r < 4; ++r)
        t.u[r] = cvt_pk_bf16(sW1[p0 + 2 * r][kt * 16 + lcol],
                             sW1[p0 + 2 * r + 1][kt * 16 + lcol]);
      bf[kt] = t.v;
    }
    int w2_ = isI ? (w - 4) : (w - 6);
#pragma unroll
    for (int t = 0; t < 2; ++t) {
      int row = (w2_ * 2 + t) * 16 + lcol;
      const float* base = isI ? &sAi[row][0] : &sAj[row][0];
      af[t] = pack8(*(const f32x4*)(base + k8), *(const f32x4*)(base + k8 + 4));
    }
  }
  __syncthreads();                         // all raw reads done

  // ---------------- phase 1b: MFMA + in-place writes ----------------
#pragma unroll
  for (int t = 0; t < 2; ++t) {
#pragma unroll
    for (int kt = 0; kt < 2; ++kt) {
      f32x4 d = __builtin_amdgcn_mfma_f32_16x16x32_bf16(af[t], bf[kt], zero, 0, 0, 0);
      if (w < 4) {
        int mt_ = w + t * 4;
#pragma unroll
        for (int r = 0; r < 4; ++r)
          sAp[mt_ * 16 + kb * 4 + r][kt * 16 + lcol] = d[r];
      } else {
        int isI = w < 6;
        int mt_ = (isI ? (w - 4) : (w - 6)) * 2 + t;
#pragma unroll
        for (int r = 0; r < 4; ++r) {
          float* T = isI ? &sAi[mt_ * 16 + kb * 4 + r][kt * 16 + lcol]
                         : &sAj[mt_ * 16 + kb * 4 + r][kt * 16 + lcol];
          *T = d[r];
        }
      }
    }
  }
  __syncthreads();

  // ---------------- phase 2: main compute (validated r7/r12) ----------------
  union { uint32_t u[4]; short8 v; } w2f;  // A = w2^T: row=lcol, k=k8..k8+7
#pragma unroll
  for (int r = 0; r < 4; ++r) {
    float lo = w2[(k8 + 2 * r) * 128 + lcol * 8 + h];
    float hi = w2[(k8 + 2 * r + 1) * 128 + lcol * 8 + h];
    w2f.u[r] = cvt_pk_bf16(lo, hi);
  }
  float w3v[4];
#pragma unroll
  for (int r = 0; r < 4; ++r) w3v[r] = w3[(kb * 4 + r) * 8 + h];

  f32x4 ajA[4], ajB[4];
#pragma unroll
  for (int ng = 0; ng < 4; ++ng) {
    int nl = ng * 16 + lcol;
    ajA[ng] = *(const f32x4*)&sAj[nl][k8];
    ajB[ng] = *(const f32x4*)&sAj[nl][k8 + 4];
  }

  const float* attn_b = attn + (b * NH + h) * SEQ * SEQ;
  float* out_b = out + (b * NH + h) * SEQ * SEQ;
  int bit4 = kb & 1, bit5 = kb & 2;

#pragma unroll
  for (int s = 0; s < 2; ++s) {
    int mb = w * 8 + s * 4;
    float av[4];
    int idxs[4];
#pragma unroll
    for (int ng = 0; ng < 4; ++ng) {
      idxs[ng] = (m0 + mb + kb) * SEQ + n0 + ng * 16 + lcol;
      av[ng] = attn_b[idxs[ng]];
    }
    f32x4 aiA[4], aiB[4];
#pragma unroll
    for (int mi = 0; mi < 4; ++mi) {
      aiA[mi] = *(const f32x4*)&sAi[mb + mi][k8];
      aiB[mi] = *(const f32x4*)&sAi[mb + mi][k8 + 4];
    }
#pragma unroll
    for (int ng = 0; ng < 4; ++ng) {
      int nl = ng * 16 + lcol;
      f32x4 pA[4], pB[4];
#pragma unroll
      for (int mi = 0; mi < 4; ++mi) {
        int rl = mb + mi - nl + 63;
        pA[mi] = *(const f32x4*)&sAp[rl][k8];
        pB[mi] = *(const f32x4*)&sAp[rl][k8 + 4];
      }
      __builtin_amdgcn_sched_barrier(0);
      float part[4];
#pragma unroll
      for (int mi = 0; mi < 4; ++mi) {
        f32x4 s0 = pA[mi] + aiA[mi] + ajA[ng];
        f32x4 s1 = pB[mi] + aiB[mi] + ajB[ng];
        union { uint32_t u[4]; short8 v; } ef;
        ef.u[0] = cvt_pk_bf16(fmaxf(s0[0], 0.f), fmaxf(s0[1], 0.f));
        ef.u[1] = cvt_pk_bf16(fmaxf(s0[2], 0.f), fmaxf(s0[3], 0.f));
        ef.u[2] = cvt_pk_bf16(fmaxf(s1[0], 0.f), fmaxf(s1[1], 0.f));
        ef.u[3] = cvt_pk_bf16(fmaxf(s1[2], 0.f), fmaxf(s1[3], 0.f));
        f32x4 d = __builtin_amdgcn_mfma_f32_16x16x32_bf16(w2f.v, ef.v, zero, 0, 0, 0);
        part[mi] = fmaxf(d[0], 0.f) * w3v[0] + fmaxf(d[1], 0.f) * w3v[1] +
                   fmaxf(d[2], 0.f) * w3v[2] + fmaxf(d[3], 0.f) * w3v[3];
      }
      float mineA = bit4 ? part[1] : part[0];
      float sendA = bit4 ? part[0] : part[1];
      float mineB = bit4 ? part[3] : part[2];
      float sendB = bit4 ? part[2] : part[3];
      mineA += __shfl_xor(sendA, 16, 64);
      mineB += __shfl_xor(sendB, 16, 64);
      float keep = bit5 ? mineB : mineA;
      float send = bit5 ? mineA : mineB;
      float res = keep + __shfl_xor(send, 32, 64);
      out_b[idxs[ng]] = av[ng] + res;
    }
  }
}

extern "C" void kernel_launch(void* const* d_in, const int* in_sizes, int n_in,
                              void* d_out, int out_size, void* d_ws, size_t ws_size,
                              hipStream_t stream) {
  const float* attn = (const float*)d_in[0];
  const int* bseq   = (const int*)d_in[1];
  const int* cseq   = (const int*)d_in[2];
  const float* epos = (const float*)d_in[3];
  const float* ebi  = (const float*)d_in[4];
  const float* ebj  = (const float*)d_in[5];
  const float* eci  = (const float*)d_in[6];
  const float* ecj  = (const float*)d_in[7];
  const float* w1   = (const float*)d_in[8];
  const float* w2   = (const float*)d_in[9];
  const float* w3   = (const float*)d_in[10];
  float* out = (float*)d_out;

  hipLaunchKernelGGL(dis_att_fused, dim3(512), dim3(512), 0, stream,
                     attn, bseq, cseq, epos, ebi, ebj, eci, ecj, w1, w2, w3, out);
}